// Round 14
// baseline (771.997 us; speedup 1.0000x reference)
//
#include <hip/hip_runtime.h>

// FSU-MGU cell: exact integer reimplementation.
// R14: b-partition main loop with R=2 rows/block (64 blocks) — streamed
// h-gate masks ([t][w][j][2] u64, coalesced dwordx4) are loaded ONCE per
// thread per step and applied to BOTH rows in registers (2x stream cut vs
// R13; 8 blocks/XCD keeps the 512 KB slab L2-resident). Zero inter-block
// communication in the main loop; one __syncthreads per step. x-gates
// precomputed in phase D (unchanged). srcw staging pass removed (phase C
// quantizes weights inline).

#define NBLK 256
#define NTHR 1024

// workspace layout (bytes); [0,4096) zeroed each call
#define WS_BAR_SUB   0u
#define WS_BAR_MST   1024u
#define WS_BAR_FLG   2048u
#define WS_RNGW   8192u
#define WS_RNGWI  9216u
#define WS_RNGM   10240u
#define WS_XP     8409088u     // 64*128*32 u32 (end 9,457,664)
#define WS_DT     9523200u     // 64*4096 i32 (end 10,571,776)
#define WS_XMASK  10571776u    // 64 slabs x 65536 u64: x-masks [t][w][col<2048]
                               // phase D overwrites each slab with xg[t][b][j]
#define WS_HMASK  44126208u    // 64 slabs x 65536 u64: h-masks [t][w][j][2]

struct SRng {
  unsigned mt[3][624];
  unsigned yb[3][624];
  unsigned draws[3][1248];
  int perm[3][256];
};
struct SC {
  unsigned short rows[16][1028];
  int rngw[64];
  int rngwi[64];
};
struct SD {
  unsigned xst[32*32];
};
struct SL {
  unsigned h[2][2][32];    // [buf][row][word]
  int rngm[16];
};
union SU { SRng r; SC c; SD d; SL l; };

struct FSUState {
  int A1,A2,A3,A4,A5,A6;
  unsigned sr1,sr2,sr3;
  int i1p,i1i,i2p,i2i,i3p,i3i;
  int hcur;
};

__device__ __forceinline__ unsigned mt_temper(unsigned y){
  y ^= y >> 11;
  y ^= (y << 7)  & 0x9d2c5680u;
  y ^= (y << 15) & 0xefc60000u;
  y ^= y >> 18;
  return y;
}

__device__ void mt_regen_serial(unsigned* mt){
  for (int i = 0; i < 624; i++){
    unsigned y = (mt[i] & 0x80000000u) | (mt[(i+1)%624] & 0x7fffffffu);
    mt[i] = mt[(i+397)%624] ^ (y >> 1) ^ ((y & 1u) ? 0x9908b0dfu : 0u);
  }
}

// numpy legacy RandomState: init_genrand seeding + Fisher-Yates with masked rejection.
__device__ void rng_gen(SU* sm, int* rngw, int* rngwi, int* rngm){
  const int tid = threadIdx.x;
  const int wv = tid >> 6, lane = tid & 63;
  const bool act = (wv < 3);
  if (act && lane == 0){
    unsigned* mt = sm->r.mt[wv];
    mt[0] = (unsigned)wv;  // seeds 0,1,2
    for (int i = 1; i < 624; i++)
      mt[i] = 1812433253u * (mt[i-1] ^ (mt[i-1] >> 30)) + (unsigned)i;
  }
  __syncthreads();
  for (int r = 0; r < 2; r++){
    if (act){
      unsigned* mt = sm->r.mt[wv]; unsigned* yb = sm->r.yb[wv];
      for (int i = lane; i < 623; i += 64)
        yb[i] = (mt[i] & 0x80000000u) | (mt[i+1] & 0x7fffffffu);
    }
    __syncthreads();
    if (act){
      unsigned* mt = sm->r.mt[wv]; unsigned* yb = sm->r.yb[wv];
      for (int i = lane; i < 227; i += 64){
        unsigned y = yb[i];
        mt[i] = mt[i+397] ^ (y >> 1) ^ ((y & 1u) ? 0x9908b0dfu : 0u);
      }
    }
    __syncthreads();
    if (act){
      unsigned* mt = sm->r.mt[wv]; unsigned* yb = sm->r.yb[wv];
      for (int i = 227 + lane; i < 454; i += 64){
        unsigned y = yb[i];
        mt[i] = mt[i-227] ^ (y >> 1) ^ ((y & 1u) ? 0x9908b0dfu : 0u);
      }
    }
    __syncthreads();
    if (act){
      unsigned* mt = sm->r.mt[wv]; unsigned* yb = sm->r.yb[wv];
      for (int i = 454 + lane; i < 624; i += 64){
        unsigned y = (i < 623) ? yb[i]
                   : ((mt[623] & 0x80000000u) | (mt[0] & 0x7fffffffu));
        mt[i] = mt[i-227] ^ (y >> 1) ^ ((y & 1u) ? 0x9908b0dfu : 0u);
      }
    }
    __syncthreads();
    if (act){
      unsigned* mt = sm->r.mt[wv];
      for (int i = lane; i < 624; i += 64)
        sm->r.draws[wv][r*624 + i] = mt_temper(mt[i]);
    }
    __syncthreads();
  }
  if (act && lane == 0){
    const int n = (wv == 2) ? 16 : 256;
    int* perm = sm->r.perm[wv];
    for (int i = 0; i < n; i++) perm[i] = i;
    int dp = 0, spos = 624;
    unsigned* mt = sm->r.mt[wv];
    for (int i = n - 1; i > 0; i--){
      unsigned mask = (unsigned)i;
      mask |= mask >> 1; mask |= mask >> 2; mask |= mask >> 4;
      mask |= mask >> 8; mask |= mask >> 16;
      unsigned v;
      do {
        unsigned d;
        if (dp < 1248) d = sm->r.draws[wv][dp++];
        else {
          if (spos >= 624){ mt_regen_serial(mt); spos = 0; }
          d = mt_temper(mt[spos++]);
        }
        v = d & mask;
      } while (v > (unsigned)i);
      int tmp = perm[i]; perm[i] = perm[v]; perm[v] = tmp;
    }
    int* dst = (wv == 0) ? rngw : (wv == 1) ? rngwi : rngm;
    for (int i = 0; i < n; i++) dst[i] = perm[i];
  }
}

// full-grid barrier WITH fences — publication barriers (setup)
__device__ __forceinline__ void gbar_full(unsigned char* ws, unsigned ep){
  __syncthreads();
  if (threadIdx.x == 0){
    __threadfence();
    unsigned* sub = (unsigned*)(ws + WS_BAR_SUB + (blockIdx.x & 7)*128);
    unsigned old = atomicAdd(sub, 1u);
    if (old == ep*32u - 1u){
      unsigned* mst = (unsigned*)(ws + WS_BAR_MST);
      unsigned mo = atomicAdd(mst, 1u);
      if (mo == ep*8u - 1u){
        for (int i = 0; i < 8; i++)
          __hip_atomic_store((unsigned*)(ws + WS_BAR_FLG + i*128), ep,
                             __ATOMIC_RELAXED, __HIP_MEMORY_SCOPE_AGENT);
      }
    }
    const unsigned* fl = (const unsigned*)(ws + WS_BAR_FLG + (blockIdx.x & 7)*128);
    while (__hip_atomic_load(fl, __ATOMIC_RELAXED, __HIP_MEMORY_SCOPE_AGENT) < ep)
      __builtin_amdgcn_s_sleep(8);
  }
  __syncthreads();
  __threadfence();
}

// full-grid barrier WITHOUT fences — read-completion only (WAR hazards).
__device__ __forceinline__ void gbar_nofence(unsigned char* ws, unsigned ep){
  __syncthreads();
  if (threadIdx.x == 0){
    unsigned* sub = (unsigned*)(ws + WS_BAR_SUB + (blockIdx.x & 7)*128);
    unsigned old = atomicAdd(sub, 1u);
    if (old == ep*32u - 1u){
      unsigned* mst = (unsigned*)(ws + WS_BAR_MST);
      unsigned mo = atomicAdd(mst, 1u);
      if (mo == ep*8u - 1u){
        for (int i = 0; i < 8; i++)
          __hip_atomic_store((unsigned*)(ws + WS_BAR_FLG + i*128), ep,
                             __ATOMIC_RELAXED, __HIP_MEMORY_SCOPE_AGENT);
      }
    }
    const unsigned* fl = (const unsigned*)(ws + WS_BAR_FLG + (blockIdx.x & 7)*128);
    while (__hip_atomic_load(fl, __ATOMIC_RELAXED, __HIP_MEMORY_SCOPE_AGENT) < ep)
      __builtin_amdgcn_s_sleep(8);
  }
  __syncthreads();
}

__device__ __forceinline__ int clampi(int v){
  v = v < -512 ? -512 : v;
  v = v >  512 ?  512 : v;
  return v;
}

// (x & p) | (~x & n)  ->  v_bfi_b32
__device__ __forceinline__ unsigned bfi(unsigned x, unsigned p, unsigned n){
  return (x & p) | (~x & n);
}

// one FSU step for one (b,j); returns hy
__device__ __forceinline__ int fsu_step(FSUState& st, int xgf, int xgn,
                                        int g_hf, int g_hn, const int* rngm){
  int s1v = xgf + g_hf;
  st.A1 = clampi(st.A1 + 2*s1v - 2049);
  int fg_in = (st.A1 >= 2); st.A1 -= fg_in << 1;
  st.A2 = clampi(st.A2 + ((fg_in + 1) << 1));
  int fg = (st.A2 >= 4); st.A2 -= fg << 2;
  st.A3 = clampi(st.A3 + (g_hn << 1) - 1024);
  int hnb = (st.A3 >= 2); st.A3 -= hnb << 1;

  st.sr1 = ((st.sr1 >> 1) | ((unsigned)hnb << 3)) & 0xFu;
  int ng_prod;
  {
    int cv = __popc(st.sr1) << 2;
    int bp = cv > rngm[st.i1p & 15];
    int bi = cv > rngm[st.i1i & 15];
    ng_prod = fg ? bp : (1 - bi);
    st.i1p += fg; st.i1i += 1 - fg;
  }
  st.A4 = clampi(st.A4 + (xgn << 1) - 1024);
  int inb = (st.A4 >= 2); st.A4 -= inb << 1;
  st.A5 = clampi(st.A5 + ((inb + ng_prod) << 1) - 1);
  int ng = (st.A5 >= 2); st.A5 -= ng << 1;

  st.sr2 = ((st.sr2 >> 1) | ((unsigned)ng << 3)) & 0xFu;
  int fgi;
  {
    int cv = __popc(st.sr2) << 2;
    int bp = cv > rngm[st.i2p & 15];
    int bi = cv > rngm[st.i2i & 15];
    fgi = (1 - fg) ? bp : (1 - bi);
    st.i2p += 1 - fg; st.i2i += fg;
  }
  st.sr3 = ((st.sr3 >> 1) | ((unsigned)st.hcur << 3)) & 0xFu;
  int fgp;
  {
    int cv = __popc(st.sr3) << 2;
    int bp = cv > rngm[st.i3p & 15];
    int bi = cv > rngm[st.i3i & 15];
    fgp = fg ? bp : (1 - bi);
    st.i3p += fg; st.i3i += 1 - fg;
  }
  st.A6 = clampi(st.A6 + ((ng + fgi + fgp) << 1) - 2);
  int hy = (st.A6 >= 2); st.A6 -= hy << 1;
  st.hcur = hy;
  return hy;
}

__global__ void __launch_bounds__(NTHR, 4)
fsu_kernel(const float* __restrict__ x, const float* __restrict__ hx0,
           const float* __restrict__ wih, const float* __restrict__ bih,
           const float* __restrict__ whh, const float* __restrict__ bhh,
           float* __restrict__ out, unsigned char* __restrict__ ws)
{
  __shared__ SU sm;
  const int tid = threadIdx.x;
  const int bid = blockIdx.x;

  int* rngw  = (int*)(ws + WS_RNGW);
  int* rngwi = (int*)(ws + WS_RNGWI);
  int* rngm  = (int*)(ws + WS_RNGM);
  unsigned* xp   = (unsigned*)(ws + WS_XP);
  int* Dt = (int*)(ws + WS_DT);
  unsigned long long* xmask = (unsigned long long*)(ws + WS_XMASK);
  unsigned long long* hmask = (unsigned long long*)(ws + WS_HMASK);
  unsigned* xgpool = (unsigned*)(ws + WS_XMASK);   // u32 view; slab 131072 u32

  // ---------- phase 0: RNG tables (block 0) || x bit-pack (others)
  if (bid == 0){
    rng_gen(&sm, rngw, rngwi, rngm);
  } else {
    const int gtid = (bid - 1)*NTHR + tid;
    const int lane = tid & 63;
    const int gw = gtid >> 6;
    const int nw = (NBLK-1)*(NTHR/64);
    for (int ch = gw; ch < 131072; ch += nw){            // x bits
      float v = x[(size_t)ch*64 + lane];
      unsigned long long bal = __ballot(v != 0.0f);
      if ((lane & 31) == 0) xp[ch*2 + (lane >> 5)] = (unsigned)(bal >> lane);
    }
  }
  gbar_full(ws, 1u);

  // ---------- phase C: masks + D' constants (weights quantized inline)
  // cols < 2048 (x-gates): x-region, TRANSPOSED [t][w][col] (phase D reads).
  // cols >= 2048 (h-gates): h-region, [t][w][j][2] (main-loop coalesced).
  {
    const int c0 = bid * 16;
    for (int q = tid; q < 16*1024; q += NTHR){
      int r = q >> 10, k = q & 1023;
      int col = c0 + r;
      float wv = (col < 2048) ? wih[(size_t)col*1024 + k]
                              : whh[(size_t)(col - 2048)*1024 + k];
      float cl = fminf(fmaxf(wv, -1.0f), 1.0f);
      sm.c.rows[r][k] = (unsigned short)(int)rintf((cl + 1.0f)*0.5f*256.0f);
    }
    if (tid < 64) sm.c.rngw[tid] = rngw[tid];
    if (tid >= 64 && tid < 128) sm.c.rngwi[tid - 64] = rngwi[tid - 64];
    __syncthreads();
    const bool xside = (c0 < 2048);
    for (int row = tid; row < 1024; row += NTHR){   // (t, local col)
      int t = row >> 4, lc = row & 15, col = c0 + lc;
      int rp = sm.c.rngw[t], ri = sm.c.rngwi[t];
      int hi = rp > ri ? rp : ri;
      int lo1 = (rp < ri ? rp : ri) + 1;
      bool rihi = (ri >= rp);
      const unsigned* srow = (const unsigned*)&sm.c.rows[lc][0];
      unsigned long long* xsl = xmask + (size_t)t*65536;
      unsigned long long* hsl = hmask + (size_t)t*65536;
      const int g  = (col - 2048) >> 10;
      const int jj = (col - 2048) & 1023;
      int cnti = 0, cntn = 0;
      for (int w = 0; w < 32; w++){
        unsigned pos = 0, neg = 0;
        #pragma unroll
        for (int i2 = 15; i2 >= 0; i2--){
          unsigned v2 = srow[w*16 + i2];
          int vH = (int)(v2 >> 16);
          int vL = (int)(v2 & 0xFFFFu);
          pos = (pos << 1) | ((unsigned)(hi - vH) >> 31);   // v > hi
          neg = (neg << 1) | ((unsigned)(vH - lo1) >> 31);  // v <= lo
          pos = (pos << 1) | ((unsigned)(hi - vL) >> 31);
          neg = (neg << 1) | ((unsigned)(vL - lo1) >> 31);
        }
        unsigned long long mval = (unsigned long long)pos
                                | ((unsigned long long)neg << 32);
        if (xside) xsl[(size_t)w*2048 + col] = mval;
        else       hsl[((size_t)w*1024 + jj)*2 + g] = mval;
        cnti += rihi ? __popc(pos) : (32 - __popc(neg));    // count(src > ri)
        cntn += __popc(neg);
      }
      float bv = (col < 2048) ? bih[col] : bhh[col - 2048];
      float bc = fminf(fmaxf(bv, -1.0f), 1.0f);
      int sb = (int)rintf((bc + 1.0f)*0.5f*256.0f);
      Dt[t*4096 + col] = 1024 - cnti - cntn + ((sb > rp) ? 1 : 0);
    }
  }
  gbar_full(ws, 2u);

  // ---------- phase D: x-gates for all t; coalesced reads, acc[32] in regs.
  {
    const int tD = bid & 63, bq = bid >> 6;
    {
      int bl = tid >> 5, w = tid & 31;
      sm.d.xst[bl*32 + w] = xp[((size_t)tD*128 + bq*32 + bl)*32 + w];
    }
    __syncthreads();
    const int jcol = tid;
    const int dA = Dt[tD*4096 + jcol] + 2048;
    const int dB = Dt[tD*4096 + 1024 + jcol] + 2048;
    const unsigned dpack = (unsigned)dA | ((unsigned)dB << 16);
    const unsigned long long* mtb = xmask + (size_t)tD*65536;
    unsigned acc[32];
    #pragma unroll
    for (int b = 0; b < 32; b++) acc[b] = 0;
    for (int w = 0; w < 32; w++){
      unsigned long long a = mtb[(size_t)w*2048 + jcol];
      unsigned long long g = mtb[(size_t)w*2048 + 1024 + jcol];
      unsigned alo = (unsigned)a, ahi = (unsigned)(a >> 32);
      unsigned glo = (unsigned)g, ghi = (unsigned)(g >> 32);
      #pragma unroll
      for (int b = 0; b < 32; b++){
        unsigned xw = sm.d.xst[b*32 + w];
        acc[b] += __popc(bfi(xw, alo, ahi))
                + (__popc(bfi(xw, glo, ghi)) << 16);
      }
    }
    gbar_nofence(ws, 3u);
    unsigned* xgst = xgpool + (size_t)tD*131072;
    #pragma unroll
    for (int b = 0; b < 32; b++)
      xgst[(size_t)(bq*32 + b)*1024 + jcol] = acc[b] + dpack;
  }
  gbar_full(ws, 4u);

  // ---------- main recurrence: 2 batch rows per block, fully local
  if (bid >= 64) return;
  const int b0r = bid*2;
  const int j = tid;

  if (tid < 16) sm.l.rngm[tid] = rngm[tid];

  FSUState s0, s1;
  s0.A1=0;s0.A2=0;s0.A3=0;s0.A4=0;s0.A5=0;s0.A6=0;
  s0.sr1=10u;s0.sr2=10u;s0.sr3=10u;
  s0.i1p=0;s0.i1i=0;s0.i2p=0;s0.i2i=0;s0.i3p=0;s0.i3i=0;
  s1 = s0;
  {
    s0.hcur = (hx0[(size_t)b0r*1024 + j] != 0.0f) ? 1 : 0;
    s1.hcur = (hx0[(size_t)(b0r+1)*1024 + j] != 0.0f) ? 1 : 0;
    unsigned long long bal0 = __ballot(s0.hcur);
    unsigned long long bal1 = __ballot(s1.hcur);
    if ((tid & 31) == 0){
      sm.l.h[0][0][tid >> 5] = (unsigned)(bal0 >> (tid & 32));
      sm.l.h[0][1][tid >> 5] = (unsigned)(bal1 >> (tid & 32));
    }
  }
  __syncthreads();

  int cur = 0;
  for (int t = 0; t < 64; t++){
    const unsigned xg0 = xgpool[(size_t)t*131072 + (size_t)b0r*1024 + j];
    const unsigned xg1 = xgpool[(size_t)t*131072 + (size_t)(b0r+1)*1024 + j];
    const int dhf = Dt[t*4096 + 2048 + j];
    const int dhn = Dt[t*4096 + 3072 + j];

    // h-gate popc: 32 mask pairs loaded ONCE, applied to both rows
    const ulonglong2* mrow = (const ulonglong2*)(hmask + (size_t)t*65536) + j;
    const uint4* hq40 = (const uint4*)sm.l.h[cur][0];
    const uint4* hq41 = (const uint4*)sm.l.h[cur][1];
    int s2a=0, s3a=0, s2b=0, s3b=0;
    #pragma unroll
    for (int wq = 0; wq < 8; wq++){
      uint4 h0 = hq40[wq];
      uint4 h1 = hq41[wq];
      {
        ulonglong2 m = mrow[(size_t)(wq*4 + 0)*1024];
        unsigned px = (unsigned)m.x, nx = (unsigned)(m.x >> 32);
        unsigned py = (unsigned)m.y, ny = (unsigned)(m.y >> 32);
        s2a += __popc(bfi(h0.x, px, nx)); s3a += __popc(bfi(h0.x, py, ny));
        s2b += __popc(bfi(h1.x, px, nx)); s3b += __popc(bfi(h1.x, py, ny));
      }
      {
        ulonglong2 m = mrow[(size_t)(wq*4 + 1)*1024];
        unsigned px = (unsigned)m.x, nx = (unsigned)(m.x >> 32);
        unsigned py = (unsigned)m.y, ny = (unsigned)(m.y >> 32);
        s2a += __popc(bfi(h0.y, px, nx)); s3a += __popc(bfi(h0.y, py, ny));
        s2b += __popc(bfi(h1.y, px, nx)); s3b += __popc(bfi(h1.y, py, ny));
      }
      {
        ulonglong2 m = mrow[(size_t)(wq*4 + 2)*1024];
        unsigned px = (unsigned)m.x, nx = (unsigned)(m.x >> 32);
        unsigned py = (unsigned)m.y, ny = (unsigned)(m.y >> 32);
        s2a += __popc(bfi(h0.z, px, nx)); s3a += __popc(bfi(h0.z, py, ny));
        s2b += __popc(bfi(h1.z, px, nx)); s3b += __popc(bfi(h1.z, py, ny));
      }
      {
        ulonglong2 m = mrow[(size_t)(wq*4 + 3)*1024];
        unsigned px = (unsigned)m.x, nx = (unsigned)(m.x >> 32);
        unsigned py = (unsigned)m.y, ny = (unsigned)(m.y >> 32);
        s2a += __popc(bfi(h0.w, px, nx)); s3a += __popc(bfi(h0.w, py, ny));
        s2b += __popc(bfi(h1.w, px, nx)); s3b += __popc(bfi(h1.w, py, ny));
      }
    }

    int hy0 = fsu_step(s0, (int)(xg0 & 0xFFFFu) - 2048, (int)(xg0 >> 16) - 2048,
                       dhf + s2a, dhn + s3a, sm.l.rngm);
    int hy1 = fsu_step(s1, (int)(xg1 & 0xFFFFu) - 2048, (int)(xg1 >> 16) - 2048,
                       dhf + s2b, dhn + s3b, sm.l.rngm);

    {
      unsigned long long bal0 = __ballot(hy0);
      unsigned long long bal1 = __ballot(hy1);
      if ((tid & 31) == 0){
        sm.l.h[cur ^ 1][0][tid >> 5] = (unsigned)(bal0 >> (tid & 32));
        sm.l.h[cur ^ 1][1][tid >> 5] = (unsigned)(bal1 >> (tid & 32));
      }
    }
    out[(size_t)t*131072 + (size_t)b0r*1024 + j] = (float)hy0;
    out[(size_t)t*131072 + (size_t)(b0r+1)*1024 + j] = (float)hy1;
    __syncthreads();   // the ONLY per-step synchronization
    cur ^= 1;
  }
}

extern "C" void kernel_launch(void* const* d_in, const int* in_sizes, int n_in,
                              void* d_out, int out_size, void* d_ws, size_t ws_size,
                              hipStream_t stream)
{
  (void)in_sizes; (void)n_in; (void)out_size; (void)ws_size;
  const float* x   = (const float*)d_in[0];
  const float* hx0 = (const float*)d_in[1];
  const float* wih = (const float*)d_in[2];
  const float* bih = (const float*)d_in[3];
  const float* whh = (const float*)d_in[4];
  const float* bhh = (const float*)d_in[5];
  float* out = (float*)d_out;
  unsigned char* ws = (unsigned char*)d_ws;

  hipMemsetAsync(d_ws, 0, 4096, stream);

  void* args[] = { (void*)&x, (void*)&hx0, (void*)&wih, (void*)&bih,
                   (void*)&whh, (void*)&bhh, (void*)&out, (void*)&ws };
  hipLaunchCooperativeKernel(reinterpret_cast<void*>(fsu_kernel),
                             dim3(NBLK), dim3(NTHR), args, 0, stream);
}